// Round 7
// baseline (275.392 us; speedup 1.0000x reference)
//
#include <hip/hip_runtime.h>

#define NEGV (-1.0e9f)

typedef __bf16 bf16_t;
typedef __bf16 bf16x8 __attribute__((ext_vector_type(8)));
typedef __bf16 bf16x4 __attribute__((ext_vector_type(4)));
typedef float  f32x4  __attribute__((ext_vector_type(4)));

// async global->LDS, 16B per lane; LDS dest is wave-uniform base + lane*16
__device__ __forceinline__ void gld16(const void* g, void* l) {
    __builtin_amdgcn_global_load_lds(
        (const __attribute__((address_space(1))) void*)g,
        (__attribute__((address_space(3))) void*)l, 16, 0, 0);
}

// ===========================================================================
// Triple-buffered counted-vmcnt mainloops (round-4 verified best), BK=32.
// LDS layout per operand tile (rows packed 2-per-128B LDS row):
//   byte = (r>>1)*128 + (r&1)*64 + p*16; phys chunk p holds logical p^((r>>1)&3).
//   2-way bank aliasing on ds_read_b128 (free, m136); staged LINEAR LDS dest +
//   inverse-swizzled GLOBAL source.  Measured 0 conflicts.
// Stage tile kt+2 during tile kt (buffer 2 away from read buffer -> race-free);
// boundary wait vmcnt(4)/(3) keeps tile kt+2's loads IN FLIGHT across barrier.
// ===========================================================================

#define MMR(AF, IB)                                                                        \
    acc[IB][0] = __builtin_amdgcn_mfma_f32_16x16x32_bf16(AF, b0, acc[IB][0], 0, 0, 0);     \
    acc[IB][1] = __builtin_amdgcn_mfma_f32_16x16x32_bf16(AF, b1, acc[IB][1], 0, 0, 0);     \
    acc[IB][2] = __builtin_amdgcn_mfma_f32_16x16x32_bf16(AF, b2, acc[IB][2], 0, 0, 0);     \
    acc[IB][3] = __builtin_amdgcn_mfma_f32_16x16x32_bf16(AF, b3, acc[IB][3], 0, 0, 0)

// ---- 256x256 tile, 8 waves (2M x 4N), acc[8][4], LDS 3 x 32K = 96 KiB ----
__device__ __forceinline__ void ml256x256(
    const bf16_t* __restrict__ A, const bf16_t* __restrict__ B,
    int ldA, int ldB, int nkt, char* smem, int tid, f32x4 acc[8][4])
{
    const int w = tid >> 6, lane = tid & 63;
    const int wm = w & 1, wn = w >> 1;
    const int l16 = lane & 15, quad = lane >> 4;

    const int g0 = 2 * (tid >> 3) + ((tid >> 2) & 1);
    const int c0 = ((tid & 3) ^ ((tid >> 3) & 3)) * 8;
    const bf16_t* pa0 = A + (size_t)g0 * ldA + c0;
    const bf16_t* pa1 = pa0 + (size_t)128 * ldA;
    const bf16_t* pb0 = B + (size_t)g0 * ldB + c0;
    const bf16_t* pb1 = pb0 + (size_t)128 * ldB;
    char* const stA = smem + (w << 10);
    char* const stB = smem + 16384 + (w << 10);

    const int rowo = (l16 >> 1) * 128 + (l16 & 1) * 64 + ((quad ^ ((l16 >> 1) & 3)) << 4);
    const char* rdA = smem + (wm << 13) + rowo;
    const char* rdB = smem + 16384 + (wn << 12) + rowo;

#define STG6(BO) do { gld16(pa0, stA + (BO)); gld16(pa1, stA + (BO) + 8192);   \
                      gld16(pb0, stB + (BO)); gld16(pb1, stB + (BO) + 8192);   \
                      pa0 += 32; pa1 += 32; pb0 += 32; pb1 += 32; } while (0)

    STG6(0);
    if (nkt > 1) {
        STG6(32768);
        asm volatile("s_waitcnt vmcnt(4)" ::: "memory");
    } else {
        asm volatile("s_waitcnt vmcnt(0)" ::: "memory");
    }
    __builtin_amdgcn_s_barrier();

    int ro = 0, so = 65536;
    for (int kt = 0; kt < nkt; ++kt) {
        const char* ra = rdA + ro;
        const char* rb = rdB + ro;
        bf16x8 a0 = *(const bf16x8*)(ra);
        bf16x8 a1 = *(const bf16x8*)(ra + 1024);
        bf16x8 a2 = *(const bf16x8*)(ra + 2048);
        bf16x8 a3 = *(const bf16x8*)(ra + 3072);
        bf16x8 b0 = *(const bf16x8*)(rb);
        bf16x8 b1 = *(const bf16x8*)(rb + 1024);
        bf16x8 b2 = *(const bf16x8*)(rb + 2048);
        bf16x8 b3 = *(const bf16x8*)(rb + 3072);
        bf16x8 a4 = *(const bf16x8*)(ra + 4096);
        bf16x8 a5 = *(const bf16x8*)(ra + 5120);
        bf16x8 a6 = *(const bf16x8*)(ra + 6144);
        bf16x8 a7 = *(const bf16x8*)(ra + 7168);
        const bool st = (kt + 2) < nkt;
        if (st) STG6(so);
        asm volatile("s_waitcnt lgkmcnt(4)" ::: "memory");
        __builtin_amdgcn_sched_barrier(0);
        __builtin_amdgcn_s_setprio(1);
        MMR(a0, 0); MMR(a1, 1); MMR(a2, 2); MMR(a3, 3);
        __builtin_amdgcn_s_setprio(0);
        asm volatile("s_waitcnt lgkmcnt(0)" ::: "memory");
        __builtin_amdgcn_sched_barrier(0);
        __builtin_amdgcn_s_setprio(1);
        MMR(a4, 4); MMR(a5, 5); MMR(a6, 6); MMR(a7, 7);
        __builtin_amdgcn_s_setprio(0);
        if (st) asm volatile("s_waitcnt vmcnt(4)" ::: "memory");
        else    asm volatile("s_waitcnt vmcnt(0)" ::: "memory");
        __builtin_amdgcn_s_barrier();
        ro = (ro == 65536) ? 0 : (ro + 32768);
        so = (so == 65536) ? 0 : (so + 32768);
    }
#undef STG6
}

// ---- 256x128 tile, 8 waves (4M x 2N), acc[4][4], LDS 3 x 24K = 72 KiB ----
__device__ __forceinline__ void ml256x128(
    const bf16_t* __restrict__ A, const bf16_t* __restrict__ B,
    int ldA, int ldB, int nkt, char* smem, int tid, f32x4 acc[4][4])
{
    const int w = tid >> 6, lane = tid & 63;
    const int wm = w & 3, wn = w >> 2;
    const int l16 = lane & 15, quad = lane >> 4;

    const int g0 = 2 * (tid >> 3) + ((tid >> 2) & 1);
    const int c0 = ((tid & 3) ^ ((tid >> 3) & 3)) * 8;
    const bf16_t* pa0 = A + (size_t)g0 * ldA + c0;
    const bf16_t* pa1 = pa0 + (size_t)128 * ldA;
    const bf16_t* pb0 = B + (size_t)g0 * ldB + c0;
    char* const stA = smem + (w << 10);
    char* const stB = smem + 16384 + (w << 10);

    const int rowo = (l16 >> 1) * 128 + (l16 & 1) * 64 + ((quad ^ ((l16 >> 1) & 3)) << 4);
    const char* rdA = smem + (wm << 12) + rowo;
    const char* rdB = smem + 16384 + (wn << 12) + rowo;

#define STG3(BO) do { gld16(pa0, stA + (BO)); gld16(pa1, stA + (BO) + 8192);   \
                      gld16(pb0, stB + (BO));                                  \
                      pa0 += 32; pa1 += 32; pb0 += 32; } while (0)

    STG3(0);
    if (nkt > 1) {
        STG3(24576);
        asm volatile("s_waitcnt vmcnt(3)" ::: "memory");
    } else {
        asm volatile("s_waitcnt vmcnt(0)" ::: "memory");
    }
    __builtin_amdgcn_s_barrier();

    int ro = 0, so = 49152;
    for (int kt = 0; kt < nkt; ++kt) {
        const char* ra = rdA + ro;
        const char* rb = rdB + ro;
        bf16x8 a0 = *(const bf16x8*)(ra);
        bf16x8 a1 = *(const bf16x8*)(ra + 1024);
        bf16x8 a2 = *(const bf16x8*)(ra + 2048);
        bf16x8 a3 = *(const bf16x8*)(ra + 3072);
        bf16x8 b0 = *(const bf16x8*)(rb);
        bf16x8 b1 = *(const bf16x8*)(rb + 1024);
        bf16x8 b2 = *(const bf16x8*)(rb + 2048);
        bf16x8 b3 = *(const bf16x8*)(rb + 3072);
        const bool st = (kt + 2) < nkt;
        if (st) STG3(so);
        asm volatile("s_waitcnt lgkmcnt(0)" ::: "memory");
        __builtin_amdgcn_sched_barrier(0);
        __builtin_amdgcn_s_setprio(1);
        MMR(a0, 0); MMR(a1, 1); MMR(a2, 2); MMR(a3, 3);
        __builtin_amdgcn_s_setprio(0);
        if (st) asm volatile("s_waitcnt vmcnt(3)" ::: "memory");
        else    asm volatile("s_waitcnt vmcnt(0)" ::: "memory");
        __builtin_amdgcn_s_barrier();
        ro = (ro == 49152) ? 0 : (ro + 24576);
        so = (so == 49152) ? 0 : (so + 24576);
    }
#undef STG3
}

// ---- pv variant: A = U(bf16, unnormalized exp) reg-staged with per-(row,
// 64-chunk) scale applied in flight -> SAME LDS image as gld16 would make;
// B = VT via gld16.  P is never materialized in HBM. ----
__device__ __forceinline__ bf16x8 scale8(bf16x8 u, float c) {
    bf16x8 o;
#pragma unroll
    for (int j = 0; j < 8; ++j) o[j] = (bf16_t)((float)u[j] * c);
    return o;
}

__device__ __forceinline__ void ml_pv(
    const bf16_t* __restrict__ A, const float* __restrict__ scA,
    const bf16_t* __restrict__ B,
    int ldA, int ldB, int nkt, char* smem, int tid, f32x4 acc[4][4])
{
    const int w = tid >> 6, lane = tid & 63;
    const int wm = w & 3, wn = w >> 2;
    const int l16 = lane & 15, quad = lane >> 4;

    const int g0 = 2 * (tid >> 3) + ((tid >> 2) & 1);
    const int c0 = ((tid & 3) ^ ((tid >> 3) & 3)) * 8;
    const bf16_t* pa0 = A + (size_t)g0 * ldA + c0;
    const bf16_t* pa1 = pa0 + (size_t)128 * ldA;
    const bf16_t* pb0 = B + (size_t)g0 * ldB + c0;
    const float* sc0 = scA + g0 * 32;
    const float* sc1 = sc0 + 128 * 32;

    char* const stB = smem + 16384 + (w << 10);
    char* const wA0 = smem + tid * 16;          // == linear gld16 dest, group 0
    char* const wA1 = smem + 8192 + tid * 16;   // group 1

    const int rowo = (l16 >> 1) * 128 + (l16 & 1) * 64 + ((quad ^ ((l16 >> 1) & 3)) << 4);
    const char* rdA = smem + (wm << 12) + rowo;
    const char* rdB = smem + 16384 + (wn << 12) + rowo;

    // prologue: stage tiles 0,1 (A: load->scale->ds_write; B: gld16); full drain
    {
        bf16x8 x00 = *(const bf16x8*)(pa0);
        bf16x8 x01 = *(const bf16x8*)(pa1);
        bf16x8 x10 = *(const bf16x8*)(pa0 + 32);
        bf16x8 x11 = *(const bf16x8*)(pa1 + 32);
        gld16(pb0, stB + 0);     pb0 += 32;
        gld16(pb0, stB + 24576); pb0 += 32;
        const float c00 = sc0[c0 >> 6],        c01 = sc1[c0 >> 6];
        const float c10 = sc0[(32 + c0) >> 6], c11 = sc1[(32 + c0) >> 6];
        *(bf16x8*)(wA0)         = scale8(x00, c00);
        *(bf16x8*)(wA1)         = scale8(x01, c01);
        *(bf16x8*)(wA0 + 24576) = scale8(x10, c10);
        *(bf16x8*)(wA1 + 24576) = scale8(x11, c11);
        asm volatile("s_waitcnt vmcnt(0) lgkmcnt(0)" ::: "memory");
        __builtin_amdgcn_s_barrier();
    }

    int ro = 0, so = 49152;
    for (int kt = 0; kt < nkt; ++kt) {
        const bool st = (kt + 2) < nkt;
        bf16x8 x0, x1; float ca0 = 0.f, ca1 = 0.f;
        if (st) {
            x0 = *(const bf16x8*)(pa0 + (size_t)(kt + 2) * 32);
            x1 = *(const bf16x8*)(pa1 + (size_t)(kt + 2) * 32);
            const int ch = ((kt + 2) * 32 + c0) >> 6;
            ca0 = sc0[ch]; ca1 = sc1[ch];
            gld16(pb0, stB + so); pb0 += 32;
        }
        const char* ra = rdA + ro;
        const char* rb = rdB + ro;
        bf16x8 a0 = *(const bf16x8*)(ra);
        bf16x8 a1 = *(const bf16x8*)(ra + 1024);
        bf16x8 a2 = *(const bf16x8*)(ra + 2048);
        bf16x8 a3 = *(const bf16x8*)(ra + 3072);
        bf16x8 b0 = *(const bf16x8*)(rb);
        bf16x8 b1 = *(const bf16x8*)(rb + 1024);
        bf16x8 b2 = *(const bf16x8*)(rb + 2048);
        bf16x8 b3 = *(const bf16x8*)(rb + 3072);
        asm volatile("s_waitcnt lgkmcnt(0)" ::: "memory");
        __builtin_amdgcn_sched_barrier(0);
        __builtin_amdgcn_s_setprio(1);
        MMR(a0, 0); MMR(a1, 1); MMR(a2, 2); MMR(a3, 3);
        __builtin_amdgcn_s_setprio(0);
        if (st) {
            // compiler inserts the exact vmcnt wait for x0/x1 here; that wait
            // also retires all older vmem (incl. B gld16 of tile kt+1).
            *(bf16x8*)(wA0 + so) = scale8(x0, ca0);
            *(bf16x8*)(wA1 + so) = scale8(x1, ca1);
        } else {
            asm volatile("s_waitcnt vmcnt(0)" ::: "memory");
        }
        asm volatile("s_waitcnt lgkmcnt(0)" ::: "memory");  // ds_writes visible
        __builtin_amdgcn_s_barrier();
        ro = (ro == 49152) ? 0 : (ro + 24576);
        so = (so == 49152) ? 0 : (so + 24576);
    }
}

// ---------------------------------------------------------------------------
__global__ __launch_bounds__(256)
void convert_x_kernel(const float* __restrict__ x, bf16_t* __restrict__ xb)
{
    const size_t i = ((size_t)blockIdx.x * 256 + threadIdx.x) * 8;
    float4 a = *(const float4*)&x[i];
    float4 b = *(const float4*)&x[i + 4];
    bf16x8 o;
    o[0] = (bf16_t)a.x; o[1] = (bf16_t)a.y; o[2] = (bf16_t)a.z; o[3] = (bf16_t)a.w;
    o[4] = (bf16_t)b.x; o[5] = (bf16_t)b.y; o[6] = (bf16_t)b.z; o[7] = (bf16_t)b.w;
    *(bf16x8*)&xb[i] = o;
}

// All three W [1024x1024] fp32 -> WT bf16 transposed, z selects matrix
__global__ __launch_bounds__(256)
void transpose_w_kernel(const float* __restrict__ W0, const float* __restrict__ W1,
                        const float* __restrict__ W2, bf16_t* __restrict__ WT)
{
    __shared__ float t[32][33];
    const float* W = (blockIdx.z == 0) ? W0 : (blockIdx.z == 1) ? W1 : W2;
    bf16_t* WTz = WT + (size_t)blockIdx.z * 1024 * 1024;
    const int k0 = blockIdx.y * 32, n0 = blockIdx.x * 32;
    const int r = threadIdx.x >> 3, c4 = (threadIdx.x & 7) * 4;
    float4 v = *(const float4*)&W[(size_t)(k0 + r) * 1024 + n0 + c4];
    t[r][c4 + 0] = v.x; t[r][c4 + 1] = v.y; t[r][c4 + 2] = v.z; t[r][c4 + 3] = v.w;
    __syncthreads();
    bf16x4 o;
#pragma unroll
    for (int j = 0; j < 4; ++j) o[j] = (bf16_t)t[c4 + j][r];
    *(bf16x4*)&WTz[(size_t)(n0 + r) * 1024 + k0 + c4] = o;
}

// ---------------------------------------------------------------------------
// QK projection: C[M,2048] bf16 = xb[M,1024] x WT[2048,1024]^T + (bq|bk)
// ---------------------------------------------------------------------------
__global__ __launch_bounds__(512, 2)
void gemm_qk256(const bf16_t* __restrict__ A, const bf16_t* __restrict__ Bt,
                const float* __restrict__ bq, const float* __restrict__ bk,
                bf16_t* __restrict__ C, int N, int Kd)
{
    __shared__ __align__(16) char smem[98304];
    int bid = blockIdx.y * 8 + blockIdx.x;
    bid = (bid & 7) * 32 + (bid >> 3);              // XCD chunking (256%8==0)
    const int n0 = (bid & 7) * 256;
    const int m0 = (bid >> 3) * 256;
    const int tid = threadIdx.x;

    f32x4 acc[8][4];
#pragma unroll
    for (int i = 0; i < 8; ++i)
#pragma unroll
        for (int j = 0; j < 4; ++j) acc[i][j] = (f32x4)(0.0f);

    ml256x256(A + (size_t)m0 * Kd, Bt + (size_t)n0 * Kd, Kd, Kd, Kd >> 5,
              smem, tid, acc);

    const int w = tid >> 6, lane = tid & 63;
    const int wm = w & 1, wn = w >> 1, quad = lane >> 4, l16 = lane & 15;
#pragma unroll
    for (int j = 0; j < 4; ++j) {
        const int col = n0 + wn * 64 + j * 16 + l16;
        const float bval = (col < 1024) ? bq[col] : bk[col - 1024];
#pragma unroll
        for (int i = 0; i < 8; ++i) {
            const int row = m0 + wm * 128 + i * 16 + quad * 4;
#pragma unroll
            for (int r = 0; r < 4; ++r)
                C[(size_t)(row + r) * N + col] = (bf16_t)(acc[i][j][r] + bval);
        }
    }
}

// ---------------------------------------------------------------------------
// V^T projection: VT[1024, 8192] = WvT[1024,1024] x xb[8192,1024]^T + bv
// ---------------------------------------------------------------------------
__global__ __launch_bounds__(512, 2)
void gemm_vt256(const bf16_t* __restrict__ WvT, const bf16_t* __restrict__ xb,
                const float* __restrict__ bv, bf16_t* __restrict__ VT,
                int N, int Kd)
{
    __shared__ __align__(16) char smem[73728];
    int bid = blockIdx.y * 64 + blockIdx.x;
    bid = (bid & 7) * 32 + (bid >> 3);              // XCD chunking
    const int m0 = (bid >> 6) * 256;     // d
    const int n0 = (bid & 63) * 128;     // b*L + l
    const int tid = threadIdx.x;

    f32x4 acc[4][4];
#pragma unroll
    for (int i = 0; i < 4; ++i)
#pragma unroll
        for (int j = 0; j < 4; ++j) acc[i][j] = (f32x4)(0.0f);

    ml256x128(WvT + (size_t)m0 * Kd, xb + (size_t)n0 * Kd, Kd, Kd, Kd >> 5,
              smem, tid, acc);

    const int w = tid >> 6, lane = tid & 63;
    const int wm = w & 3, wn = w >> 2, quad = lane >> 4, l16 = lane & 15;
#pragma unroll
    for (int i = 0; i < 4; ++i) {
        const int row = m0 + wm * 64 + i * 16 + quad * 4;    // d index
#pragma unroll
        for (int r = 0; r < 4; ++r) {
            const float bval = bv[row + r];
#pragma unroll
            for (int j = 0; j < 4; ++j) {
                const int col = n0 + wn * 64 + j * 16 + l16;
                VT[(size_t)(row + r) * N + col] = (bf16_t)(acc[i][j][r] + bval);
            }
        }
    }
}

// ---------------------------------------------------------------------------
// Scores + BLOCKWISE softmax: 256x256 triangular tiles.  Per (row, 64-col
// chunk): m = max, sigma = sum(exp(s-m)) reduced across the 16-lane quad
// group; writes U = exp(s-m) bf16 and (m, sigma) side-stats.  Masked entries
// get exp -> 0 naturally; fully-masked chunks are zeroed later via scale=0.
// ---------------------------------------------------------------------------
__global__ __launch_bounds__(512, 2)
void scores256(const bf16_t* __restrict__ Q, const bf16_t* __restrict__ K,
               int ldq, const int* __restrict__ lengths,
               bf16_t* __restrict__ U, float2* __restrict__ stats,
               int L, int Dd, float alpha)
{
    __shared__ __align__(16) char smem[98304];
    const int b = blockIdx.z;
    const int len = lengths[b];
    int it = 0;
    while ((it + 1) * (it + 2) / 2 <= (int)blockIdx.x) ++it;
    const int jt = blockIdx.x - it * (it + 1) / 2;
    const int m0 = it * 256, n0 = jt * 256;
    const int tid = threadIdx.x;

    f32x4 acc[8][4];
#pragma unroll
    for (int i = 0; i < 8; ++i)
#pragma unroll
        for (int j = 0; j < 4; ++j) acc[i][j] = (f32x4)(0.0f);

    const bf16_t* Qb = Q + (size_t)b * L * ldq + (size_t)m0 * ldq;
    const bf16_t* Kb = K + (size_t)b * L * ldq + (size_t)n0 * ldq;
    ml256x256(Qb, Kb, ldq, ldq, Dd >> 5, smem, tid, acc);

    const int w = tid >> 6, lane = tid & 63;
    const int wm = w & 1, wn = w >> 1, quad = lane >> 4, l16 = lane & 15;
    bf16_t* Ub = U + (size_t)b * L * L;
    float2* strow = stats + (size_t)b * L * 32;
    const int chnk = (n0 >> 6) + wn;
#pragma unroll
    for (int i = 0; i < 8; ++i) {
#pragma unroll
        for (int r = 0; r < 4; ++r) {
            const int row = m0 + wm * 128 + i * 16 + quad * 4 + r;
            float sv[4];
#pragma unroll
            for (int j = 0; j < 4; ++j) {
                const int col = n0 + wn * 64 + j * 16 + l16;
                float v = acc[i][j][r] * alpha;
                if (col > row) v += NEGV;                 // causal first
                if (row >= len || col >= len) v += NEGV;  // then length mask
                sv[j] = v;
            }
            float m = fmaxf(fmaxf(sv[0], sv[1]), fmaxf(sv[2], sv[3]));
            m = fmaxf(m, __shfl_xor(m, 1, 64));
            m = fmaxf(m, __shfl_xor(m, 2, 64));
            m = fmaxf(m, __shfl_xor(m, 4, 64));
            m = fmaxf(m, __shfl_xor(m, 8, 64));
            float ssum = 0.f;
#pragma unroll
            for (int j = 0; j < 4; ++j) {
                sv[j] = __expf(sv[j] - m);
                ssum += sv[j];
            }
            ssum += __shfl_xor(ssum, 1, 64);
            ssum += __shfl_xor(ssum, 2, 64);
            ssum += __shfl_xor(ssum, 4, 64);
            ssum += __shfl_xor(ssum, 8, 64);
#pragma unroll
            for (int j = 0; j < 4; ++j)
                Ub[(size_t)row * L + n0 + wn * 64 + j * 16 + l16] = (bf16_t)sv[j];
            if (l16 == 0) strow[(size_t)row * 32 + chnk] = make_float2(m, ssum);
        }
    }
}

// ---------------------------------------------------------------------------
// Finalize: per (b,row) reduce 32 chunk-stats -> per-chunk scale
// c = exp(m_c - M) / D, D = sum sigma_c*exp(m_c - M).  32 lanes per row.
// Only chunks < (row/256+1)*4 are valid (tiles beyond causal bound never ran).
// ---------------------------------------------------------------------------
__global__ __launch_bounds__(256)
void sm_finalize(const float2* __restrict__ stats, float* __restrict__ scale, int L)
{
    const int t = threadIdx.x;
    const int c = t & 31;
    const int row = blockIdx.x * 8 + (t >> 5);
    const size_t base = ((size_t)blockIdx.y * L + row) * 32;
    const int nch = ((row >> 8) + 1) << 2;
    float m_c = -3.0e38f, s_c = 0.f;
    if (c < nch) { float2 st = stats[base + c]; m_c = st.x; s_c = st.y; }
    float M = m_c;
    M = fmaxf(M, __shfl_xor(M, 1, 64));
    M = fmaxf(M, __shfl_xor(M, 2, 64));
    M = fmaxf(M, __shfl_xor(M, 4, 64));
    M = fmaxf(M, __shfl_xor(M, 8, 64));
    M = fmaxf(M, __shfl_xor(M, 16, 64));
    const float e = __expf(m_c - M);
    float d = s_c * e;
    d += __shfl_xor(d, 1, 64);
    d += __shfl_xor(d, 2, 64);
    d += __shfl_xor(d, 4, 64);
    d += __shfl_xor(d, 8, 64);
    d += __shfl_xor(d, 16, 64);
    if (c < nch) scale[base + c] = e / d;
}

// ---------------------------------------------------------------------------
// PV: O[b][L,D] fp32 = (U*scale)[b][L,L] x V^T (VT layout [d][b][l], ld 8192).
// A-operand staged from U with inline scale (P never hits HBM).
// ---------------------------------------------------------------------------
__global__ __launch_bounds__(512, 2)
void pv256(const bf16_t* __restrict__ U, int ldp, const float* __restrict__ scale,
           const bf16_t* __restrict__ VT, int ldv,
           float* __restrict__ O, int L, int Dd)
{
    __shared__ __align__(16) char smem[73728];
    const int b = blockIdx.z;
    int bid = blockIdx.y * 8 + blockIdx.x;
    bid = (bid & 7) * 8 + (bid >> 3);            // XCD chunking
    const int mt = 7 - (bid >> 3);               // heavy first
    const int m0 = mt * 256, n0 = (bid & 7) * 128;
    const int tid = threadIdx.x;

    f32x4 acc[4][4];
#pragma unroll
    for (int i = 0; i < 4; ++i)
#pragma unroll
        for (int j = 0; j < 4; ++j) acc[i][j] = (f32x4)(0.0f);

    const int nkt = (m0 + 256) >> 5;   // U[i][j]==0 for j>i within written range
    const bf16_t* Pb = U + (size_t)b * L * ldp + (size_t)m0 * ldp;
    const float* scA = scale + ((size_t)b * L + m0) * 32;
    const bf16_t* Vb = VT + (size_t)b * L + (size_t)n0 * ldv;
    ml_pv(Pb, scA, Vb, ldp, ldv, nkt, smem, tid, acc);

    float* Ob = O + (size_t)b * L * Dd;
    const int w = tid >> 6, lane = tid & 63;
    const int wm = w & 3, wn = w >> 2, quad = lane >> 4, l16 = lane & 15;
#pragma unroll
    for (int i = 0; i < 4; ++i) {
        const int row = m0 + wm * 64 + i * 16 + quad * 4;
#pragma unroll
        for (int j = 0; j < 4; ++j) {
            const int col = n0 + wn * 64 + j * 16 + l16;
#pragma unroll
            for (int r = 0; r < 4; ++r)
                Ob[(size_t)(row + r) * Dd + col] = acc[i][j][r];
        }
    }
}

// ---------------------------------------------------------------------------
extern "C" void kernel_launch(void* const* d_in, const int* in_sizes, int n_in,
                              void* d_out, int out_size, void* d_ws, size_t ws_size,
                              hipStream_t stream)
{
    const float* x  = (const float*)d_in[0];
    const float* Wq = (const float*)d_in[1];
    const float* bq = (const float*)d_in[2];
    const float* Wk = (const float*)d_in[3];
    const float* bk = (const float*)d_in[4];
    const float* Wv = (const float*)d_in[5];
    const float* bv = (const float*)d_in[6];
    const int*  len = (const int*)d_in[7];
    float* out = (float*)d_out;

    const int B = 4, L = 2048, D = 1024;
    const int M = B * L;     // 8192
    const int N2 = 2 * D;    // 2048

    // Workspace (~105 MB):
    //  xb [8192][1024] bf16 = 16 MB
    //  WT [3072][1024] bf16 = 6 MB
    //  QK [8192][2048] bf16 = 32 MB  (cols 0:Q 1024:K)
    //  VT [1024][8192] bf16 = 16 MB  (layout [d][b][l])
    //  U  [4][2048][2048] bf16 = 32 MB (blockwise exp, unnormalized)
    //  stats [4][2048][32] float2 = 2 MB
    //  scale [4][2048][32] float  = 1 MB
    bf16_t* xb = (bf16_t*)d_ws;
    bf16_t* WT = xb + (size_t)M * D;
    bf16_t* QK = WT + (size_t)3 * D * D;
    bf16_t* VT = QK + (size_t)M * N2;
    bf16_t* U  = VT + (size_t)D * M;
    float2* stats = (float2*)(U + (size_t)B * L * L);
    float*  scale = (float*)(stats + (size_t)B * L * 32);

    // 1) x -> bf16
    convert_x_kernel<<<(M * D) / 2048, 256, 0, stream>>>(x, xb);

    // 2) all W transposes in one launch
    transpose_w_kernel<<<dim3(32, 32, 3), 256, 0, stream>>>(Wq, Wk, Wv, WT);

    // 3) QK projection (N=2048), 256x256 tiles, 256 blocks
    gemm_qk256<<<dim3(8, 32), 512, 0, stream>>>(xb, WT, bq, bk, QK, N2, D);

    // 4) V^T projection, 256x128 tiles, 256 blocks
    gemm_vt256<<<dim3(64, 4), 512, 0, stream>>>(
        WT + (size_t)2 * D * D, xb, bv, VT, M, D);

    // 5) scores + blockwise softmax -> U (bf16) + stats
    scores256<<<dim3(36, 1, B), 512, 0, stream>>>(
        QK, QK + 1024, N2, len, U, stats, L, D, 0.03125f);

    // 6) reduce stats -> per-(row,chunk) scales
    sm_finalize<<<dim3(L / 8, B), 256, 0, stream>>>(stats, scale, L);

    // 7) O = (U*scale) @ V, causal k-limit, heavy tiles first
    pv256<<<dim3(8, 8, 4), 512, 0, stream>>>(U, L, scale, VT, M, out, L, D);
}

// Round 8
// 246.169 us; speedup vs baseline: 1.1187x; 1.1187x over previous
//
#include <hip/hip_runtime.h>

#define NEGV (-1.0e9f)

typedef __bf16 bf16_t;
typedef __bf16 bf16x8 __attribute__((ext_vector_type(8)));
typedef __bf16 bf16x4 __attribute__((ext_vector_type(4)));
typedef float  f32x4  __attribute__((ext_vector_type(4)));

// async global->LDS, 16B per lane; LDS dest is wave-uniform base + lane*16
__device__ __forceinline__ void gld16(const void* g, void* l) {
    __builtin_amdgcn_global_load_lds(
        (const __attribute__((address_space(1))) void*)g,
        (__attribute__((address_space(3))) void*)l, 16, 0, 0);
}

// ===========================================================================
// Triple-buffered counted-vmcnt mainloops (round-4 verified best), BK=32.
// LDS layout per operand tile (rows packed 2-per-128B LDS row):
//   byte = (r>>1)*128 + (r&1)*64 + p*16; phys chunk p holds logical p^((r>>1)&3).
//   2-way bank aliasing on ds_read_b128 (free, m136); staged LINEAR LDS dest +
//   inverse-swizzled GLOBAL source.  Measured 0 conflicts.
// Stage tile kt+2 during tile kt (buffer 2 away from read buffer -> race-free);
// boundary wait vmcnt(4)/(3) keeps tile kt+2's loads IN FLIGHT across barrier.
// ===========================================================================

#define MMR(AF, IB)                                                                        \
    acc[IB][0] = __builtin_amdgcn_mfma_f32_16x16x32_bf16(AF, b0, acc[IB][0], 0, 0, 0);     \
    acc[IB][1] = __builtin_amdgcn_mfma_f32_16x16x32_bf16(AF, b1, acc[IB][1], 0, 0, 0);     \
    acc[IB][2] = __builtin_amdgcn_mfma_f32_16x16x32_bf16(AF, b2, acc[IB][2], 0, 0, 0);     \
    acc[IB][3] = __builtin_amdgcn_mfma_f32_16x16x32_bf16(AF, b3, acc[IB][3], 0, 0, 0)

// ---- 256x256 tile, 8 waves (2M x 4N), acc[8][4], LDS 3 x 32K = 96 KiB ----
__device__ __forceinline__ void ml256x256(
    const bf16_t* __restrict__ A, const bf16_t* __restrict__ B,
    int ldA, int ldB, int nkt, char* smem, int tid, f32x4 acc[8][4])
{
    const int w = tid >> 6, lane = tid & 63;
    const int wm = w & 1, wn = w >> 1;
    const int l16 = lane & 15, quad = lane >> 4;

    const int g0 = 2 * (tid >> 3) + ((tid >> 2) & 1);
    const int c0 = ((tid & 3) ^ ((tid >> 3) & 3)) * 8;
    const bf16_t* pa0 = A + (size_t)g0 * ldA + c0;
    const bf16_t* pa1 = pa0 + (size_t)128 * ldA;
    const bf16_t* pb0 = B + (size_t)g0 * ldB + c0;
    const bf16_t* pb1 = pb0 + (size_t)128 * ldB;
    char* const stA = smem + (w << 10);
    char* const stB = smem + 16384 + (w << 10);

    const int rowo = (l16 >> 1) * 128 + (l16 & 1) * 64 + ((quad ^ ((l16 >> 1) & 3)) << 4);
    const char* rdA = smem + (wm << 13) + rowo;
    const char* rdB = smem + 16384 + (wn << 12) + rowo;

#define STG6(BO) do { gld16(pa0, stA + (BO)); gld16(pa1, stA + (BO) + 8192);   \
                      gld16(pb0, stB + (BO)); gld16(pb1, stB + (BO) + 8192);   \
                      pa0 += 32; pa1 += 32; pb0 += 32; pb1 += 32; } while (0)

    STG6(0);
    if (nkt > 1) {
        STG6(32768);
        asm volatile("s_waitcnt vmcnt(4)" ::: "memory");
    } else {
        asm volatile("s_waitcnt vmcnt(0)" ::: "memory");
    }
    __builtin_amdgcn_s_barrier();

    int ro = 0, so = 65536;
    for (int kt = 0; kt < nkt; ++kt) {
        const char* ra = rdA + ro;
        const char* rb = rdB + ro;
        bf16x8 a0 = *(const bf16x8*)(ra);
        bf16x8 a1 = *(const bf16x8*)(ra + 1024);
        bf16x8 a2 = *(const bf16x8*)(ra + 2048);
        bf16x8 a3 = *(const bf16x8*)(ra + 3072);
        bf16x8 b0 = *(const bf16x8*)(rb);
        bf16x8 b1 = *(const bf16x8*)(rb + 1024);
        bf16x8 b2 = *(const bf16x8*)(rb + 2048);
        bf16x8 b3 = *(const bf16x8*)(rb + 3072);
        bf16x8 a4 = *(const bf16x8*)(ra + 4096);
        bf16x8 a5 = *(const bf16x8*)(ra + 5120);
        bf16x8 a6 = *(const bf16x8*)(ra + 6144);
        bf16x8 a7 = *(const bf16x8*)(ra + 7168);
        const bool st = (kt + 2) < nkt;
        if (st) STG6(so);
        asm volatile("s_waitcnt lgkmcnt(4)" ::: "memory");
        __builtin_amdgcn_sched_barrier(0);
        __builtin_amdgcn_s_setprio(1);
        MMR(a0, 0); MMR(a1, 1); MMR(a2, 2); MMR(a3, 3);
        __builtin_amdgcn_s_setprio(0);
        asm volatile("s_waitcnt lgkmcnt(0)" ::: "memory");
        __builtin_amdgcn_sched_barrier(0);
        __builtin_amdgcn_s_setprio(1);
        MMR(a4, 4); MMR(a5, 5); MMR(a6, 6); MMR(a7, 7);
        __builtin_amdgcn_s_setprio(0);
        if (st) asm volatile("s_waitcnt vmcnt(4)" ::: "memory");
        else    asm volatile("s_waitcnt vmcnt(0)" ::: "memory");
        __builtin_amdgcn_s_barrier();
        ro = (ro == 65536) ? 0 : (ro + 32768);
        so = (so == 65536) ? 0 : (so + 32768);
    }
#undef STG6
}

// ---- 256x128 tile, 8 waves (4M x 2N), acc[4][4], LDS 3 x 24K = 72 KiB ----
__device__ __forceinline__ void ml256x128(
    const bf16_t* __restrict__ A, const bf16_t* __restrict__ B,
    int ldA, int ldB, int nkt, char* smem, int tid, f32x4 acc[4][4])
{
    const int w = tid >> 6, lane = tid & 63;
    const int wm = w & 3, wn = w >> 2;
    const int l16 = lane & 15, quad = lane >> 4;

    const int g0 = 2 * (tid >> 3) + ((tid >> 2) & 1);
    const int c0 = ((tid & 3) ^ ((tid >> 3) & 3)) * 8;
    const bf16_t* pa0 = A + (size_t)g0 * ldA + c0;
    const bf16_t* pa1 = pa0 + (size_t)128 * ldA;
    const bf16_t* pb0 = B + (size_t)g0 * ldB + c0;
    char* const stA = smem + (w << 10);
    char* const stB = smem + 16384 + (w << 10);

    const int rowo = (l16 >> 1) * 128 + (l16 & 1) * 64 + ((quad ^ ((l16 >> 1) & 3)) << 4);
    const char* rdA = smem + (wm << 12) + rowo;
    const char* rdB = smem + 16384 + (wn << 12) + rowo;

#define STG3(BO) do { gld16(pa0, stA + (BO)); gld16(pa1, stA + (BO) + 8192);   \
                      gld16(pb0, stB + (BO));                                  \
                      pa0 += 32; pa1 += 32; pb0 += 32; } while (0)

    STG3(0);
    if (nkt > 1) {
        STG3(24576);
        asm volatile("s_waitcnt vmcnt(3)" ::: "memory");
    } else {
        asm volatile("s_waitcnt vmcnt(0)" ::: "memory");
    }
    __builtin_amdgcn_s_barrier();

    int ro = 0, so = 49152;
    for (int kt = 0; kt < nkt; ++kt) {
        const char* ra = rdA + ro;
        const char* rb = rdB + ro;
        bf16x8 a0 = *(const bf16x8*)(ra);
        bf16x8 a1 = *(const bf16x8*)(ra + 1024);
        bf16x8 a2 = *(const bf16x8*)(ra + 2048);
        bf16x8 a3 = *(const bf16x8*)(ra + 3072);
        bf16x8 b0 = *(const bf16x8*)(rb);
        bf16x8 b1 = *(const bf16x8*)(rb + 1024);
        bf16x8 b2 = *(const bf16x8*)(rb + 2048);
        bf16x8 b3 = *(const bf16x8*)(rb + 3072);
        const bool st = (kt + 2) < nkt;
        if (st) STG3(so);
        asm volatile("s_waitcnt lgkmcnt(0)" ::: "memory");
        __builtin_amdgcn_sched_barrier(0);
        __builtin_amdgcn_s_setprio(1);
        MMR(a0, 0); MMR(a1, 1); MMR(a2, 2); MMR(a3, 3);
        __builtin_amdgcn_s_setprio(0);
        if (st) asm volatile("s_waitcnt vmcnt(3)" ::: "memory");
        else    asm volatile("s_waitcnt vmcnt(0)" ::: "memory");
        __builtin_amdgcn_s_barrier();
        ro = (ro == 49152) ? 0 : (ro + 24576);
        so = (so == 49152) ? 0 : (so + 24576);
    }
#undef STG3
}

// ---------------------------------------------------------------------------
__global__ __launch_bounds__(256)
void convert_x_kernel(const float* __restrict__ x, bf16_t* __restrict__ xb)
{
    const size_t i = ((size_t)blockIdx.x * 256 + threadIdx.x) * 8;
    float4 a = *(const float4*)&x[i];
    float4 b = *(const float4*)&x[i + 4];
    bf16x8 o;
    o[0] = (bf16_t)a.x; o[1] = (bf16_t)a.y; o[2] = (bf16_t)a.z; o[3] = (bf16_t)a.w;
    o[4] = (bf16_t)b.x; o[5] = (bf16_t)b.y; o[6] = (bf16_t)b.z; o[7] = (bf16_t)b.w;
    *(bf16x8*)&xb[i] = o;
}

// All three W [1024x1024] fp32 -> WT bf16 transposed, z selects matrix
__global__ __launch_bounds__(256)
void transpose_w_kernel(const float* __restrict__ W0, const float* __restrict__ W1,
                        const float* __restrict__ W2, bf16_t* __restrict__ WT)
{
    __shared__ float t[32][33];
    const float* W = (blockIdx.z == 0) ? W0 : (blockIdx.z == 1) ? W1 : W2;
    bf16_t* WTz = WT + (size_t)blockIdx.z * 1024 * 1024;
    const int k0 = blockIdx.y * 32, n0 = blockIdx.x * 32;
    const int r = threadIdx.x >> 3, c4 = (threadIdx.x & 7) * 4;
    float4 v = *(const float4*)&W[(size_t)(k0 + r) * 1024 + n0 + c4];
    t[r][c4 + 0] = v.x; t[r][c4 + 1] = v.y; t[r][c4 + 2] = v.z; t[r][c4 + 3] = v.w;
    __syncthreads();
    bf16x4 o;
#pragma unroll
    for (int j = 0; j < 4; ++j) o[j] = (bf16_t)t[c4 + j][r];
    *(bf16x4*)&WTz[(size_t)(n0 + r) * 1024 + k0 + c4] = o;
}

// ---------------------------------------------------------------------------
// QK projection: C[M,2048] bf16 = xb[M,1024] x WT[2048,1024]^T + (bq|bk)
// ---------------------------------------------------------------------------
__global__ __launch_bounds__(512, 2)
void gemm_qk256(const bf16_t* __restrict__ A, const bf16_t* __restrict__ Bt,
                const float* __restrict__ bq, const float* __restrict__ bk,
                bf16_t* __restrict__ C, int N, int Kd)
{
    __shared__ __align__(16) char smem[98304];
    int bid = blockIdx.y * 8 + blockIdx.x;
    bid = (bid & 7) * 32 + (bid >> 3);              // XCD chunking (256%8==0)
    const int n0 = (bid & 7) * 256;
    const int m0 = (bid >> 3) * 256;
    const int tid = threadIdx.x;

    f32x4 acc[8][4];
#pragma unroll
    for (int i = 0; i < 8; ++i)
#pragma unroll
        for (int j = 0; j < 4; ++j) acc[i][j] = (f32x4)(0.0f);

    ml256x256(A + (size_t)m0 * Kd, Bt + (size_t)n0 * Kd, Kd, Kd, Kd >> 5,
              smem, tid, acc);

    const int w = tid >> 6, lane = tid & 63;
    const int wm = w & 1, wn = w >> 1, quad = lane >> 4, l16 = lane & 15;
#pragma unroll
    for (int j = 0; j < 4; ++j) {
        const int col = n0 + wn * 64 + j * 16 + l16;
        const float bval = (col < 1024) ? bq[col] : bk[col - 1024];
#pragma unroll
        for (int i = 0; i < 8; ++i) {
            const int row = m0 + wm * 128 + i * 16 + quad * 4;
#pragma unroll
            for (int r = 0; r < 4; ++r)
                C[(size_t)(row + r) * N + col] = (bf16_t)(acc[i][j][r] + bval);
        }
    }
}

// ---------------------------------------------------------------------------
// V^T projection: VT[1024, 8192] = WvT[1024,1024] x xb[8192,1024]^T + bv
// ---------------------------------------------------------------------------
__global__ __launch_bounds__(512, 2)
void gemm_vt256(const bf16_t* __restrict__ WvT, const bf16_t* __restrict__ xb,
                const float* __restrict__ bv, bf16_t* __restrict__ VT,
                int N, int Kd)
{
    __shared__ __align__(16) char smem[73728];
    int bid = blockIdx.y * 64 + blockIdx.x;
    bid = (bid & 7) * 32 + (bid >> 3);              // XCD chunking
    const int m0 = (bid >> 6) * 256;     // d
    const int n0 = (bid & 63) * 128;     // b*L + l
    const int tid = threadIdx.x;

    f32x4 acc[4][4];
#pragma unroll
    for (int i = 0; i < 4; ++i)
#pragma unroll
        for (int j = 0; j < 4; ++j) acc[i][j] = (f32x4)(0.0f);

    ml256x128(WvT + (size_t)m0 * Kd, xb + (size_t)n0 * Kd, Kd, Kd, Kd >> 5,
              smem, tid, acc);

    const int w = tid >> 6, lane = tid & 63;
    const int wm = w & 3, wn = w >> 2, quad = lane >> 4, l16 = lane & 15;
#pragma unroll
    for (int i = 0; i < 4; ++i) {
        const int row = m0 + wm * 64 + i * 16 + quad * 4;    // d index
#pragma unroll
        for (int r = 0; r < 4; ++r) {
            const float bval = bv[row + r];
#pragma unroll
            for (int j = 0; j < 4; ++j) {
                const int col = n0 + wn * 64 + j * 16 + l16;
                VT[(size_t)(row + r) * N + col] = (bf16_t)(acc[i][j][r] + bval);
            }
        }
    }
}

// ---------------------------------------------------------------------------
// Scores + BLOCKWISE softmax: 256x256 triangular tiles.  Per (row, 64-col
// chunk): m = max, sigma = sum(exp(s-m)) reduced across the 16-lane quad
// group; writes U = exp(s-m) bf16 and (m, sigma) side-stats.  Masked entries
// get exp -> 0 naturally; fully-masked chunks are zeroed later via scale=0.
// ---------------------------------------------------------------------------
__global__ __launch_bounds__(512, 2)
void scores256(const bf16_t* __restrict__ Q, const bf16_t* __restrict__ K,
               int ldq, const int* __restrict__ lengths,
               bf16_t* __restrict__ U, float2* __restrict__ stats,
               int L, int Dd, float alpha)
{
    __shared__ __align__(16) char smem[98304];
    const int b = blockIdx.z;
    const int len = lengths[b];
    int it = 0;
    while ((it + 1) * (it + 2) / 2 <= (int)blockIdx.x) ++it;
    const int jt = blockIdx.x - it * (it + 1) / 2;
    const int m0 = it * 256, n0 = jt * 256;
    const int tid = threadIdx.x;

    f32x4 acc[8][4];
#pragma unroll
    for (int i = 0; i < 8; ++i)
#pragma unroll
        for (int j = 0; j < 4; ++j) acc[i][j] = (f32x4)(0.0f);

    const bf16_t* Qb = Q + (size_t)b * L * ldq + (size_t)m0 * ldq;
    const bf16_t* Kb = K + (size_t)b * L * ldq + (size_t)n0 * ldq;
    ml256x256(Qb, Kb, ldq, ldq, Dd >> 5, smem, tid, acc);

    const int w = tid >> 6, lane = tid & 63;
    const int wm = w & 1, wn = w >> 1, quad = lane >> 4, l16 = lane & 15;
    bf16_t* Ub = U + (size_t)b * L * L;
    float2* strow = stats + (size_t)b * L * 32;
    const int chnk = (n0 >> 6) + wn;
#pragma unroll
    for (int i = 0; i < 8; ++i) {
#pragma unroll
        for (int r = 0; r < 4; ++r) {
            const int row = m0 + wm * 128 + i * 16 + quad * 4 + r;
            float sv[4];
#pragma unroll
            for (int j = 0; j < 4; ++j) {
                const int col = n0 + wn * 64 + j * 16 + l16;
                float v = acc[i][j][r] * alpha;
                if (col > row) v += NEGV;                 // causal first
                if (row >= len || col >= len) v += NEGV;  // then length mask
                sv[j] = v;
            }
            float m = fmaxf(fmaxf(sv[0], sv[1]), fmaxf(sv[2], sv[3]));
            m = fmaxf(m, __shfl_xor(m, 1, 64));
            m = fmaxf(m, __shfl_xor(m, 2, 64));
            m = fmaxf(m, __shfl_xor(m, 4, 64));
            m = fmaxf(m, __shfl_xor(m, 8, 64));
            float ssum = 0.f;
#pragma unroll
            for (int j = 0; j < 4; ++j) {
                sv[j] = __expf(sv[j] - m);
                ssum += sv[j];
            }
            ssum += __shfl_xor(ssum, 1, 64);
            ssum += __shfl_xor(ssum, 2, 64);
            ssum += __shfl_xor(ssum, 4, 64);
            ssum += __shfl_xor(ssum, 8, 64);
#pragma unroll
            for (int j = 0; j < 4; ++j)
                Ub[(size_t)row * L + n0 + wn * 64 + j * 16 + l16] = (bf16_t)sv[j];
            if (l16 == 0) strow[(size_t)row * 32 + chnk] = make_float2(m, ssum);
        }
    }
}

// ---------------------------------------------------------------------------
// Finalize + NORMALIZE: per (b,row) reduce chunk-stats -> per-chunk scale
// c = exp(m_c - M)/D, then stream the row's U prefix (cols < bound2) in
// place: P = U * c.  Fully-masked chunks get scale 0 -> exact zeros for pv.
// ---------------------------------------------------------------------------
__global__ __launch_bounds__(256)
void sm_finalize_norm(const float2* __restrict__ stats, bf16_t* __restrict__ U,
                      int L)
{
    __shared__ float sc[32];
    const int i = blockIdx.x;
    const int bound2 = ((i >> 8) + 1) << 8;     // 256-aligned causal bound
    const int nch = bound2 >> 6;                // valid 64-col chunks
    const size_t base = ((size_t)blockIdx.y * L + i) * 32;
    const int t = threadIdx.x;

    if (t < 32) {
        float m_c = -3.0e38f, s_c = 0.f;
        if (t < nch) { float2 st = stats[base + t]; m_c = st.x; s_c = st.y; }
        float M = m_c;
        M = fmaxf(M, __shfl_xor(M, 1, 64));
        M = fmaxf(M, __shfl_xor(M, 2, 64));
        M = fmaxf(M, __shfl_xor(M, 4, 64));
        M = fmaxf(M, __shfl_xor(M, 8, 64));
        M = fmaxf(M, __shfl_xor(M, 16, 64));
        const float e = __expf(m_c - M);        // 0 for invalid/masked chunks
        float d = s_c * e;
        d += __shfl_xor(d, 1, 64);
        d += __shfl_xor(d, 2, 64);
        d += __shfl_xor(d, 4, 64);
        d += __shfl_xor(d, 8, 64);
        d += __shfl_xor(d, 16, 64);
        sc[t] = e / d;
    }
    __syncthreads();

    const int j8 = t * 8;
    if (j8 < bound2) {
        bf16_t* row = U + ((size_t)blockIdx.y * L + i) * L;
        bf16x8 u = *(const bf16x8*)&row[j8];
        const float c = sc[t >> 3];
        bf16x8 o;
#pragma unroll
        for (int j = 0; j < 8; ++j) o[j] = (bf16_t)((float)u[j] * c);
        *(bf16x8*)&row[j8] = o;
    }
}

// ---------------------------------------------------------------------------
// PV: O[b][L,D] fp32 = P[b][L,L] x V^T (VT layout [d][b][l], ld 8192).
// P = normalized U (in place).  256(l) x 128(d) tiles -> 256 blocks, causal
// k-limit at 256-row granularity, heavy m-tiles first, XCD chunking.
// ---------------------------------------------------------------------------
__global__ __launch_bounds__(512, 2)
void pv256(const bf16_t* __restrict__ P, int ldp,
           const bf16_t* __restrict__ VT, int ldv,
           float* __restrict__ O, int L, int Dd)
{
    __shared__ __align__(16) char smem[73728];
    const int b = blockIdx.z;
    int bid = blockIdx.y * 8 + blockIdx.x;       // 64 per batch
    bid = (bid & 7) * 8 + (bid >> 3);            // XCD chunking
    const int mt = 7 - (bid >> 3);               // heavy first
    const int m0 = mt * 256, n0 = (bid & 7) * 128;
    const int tid = threadIdx.x;

    f32x4 acc[4][4];
#pragma unroll
    for (int i = 0; i < 4; ++i)
#pragma unroll
        for (int j = 0; j < 4; ++j) acc[i][j] = (f32x4)(0.0f);

    const int nkt = (m0 + 256) >> 5;   // P[i][j]==0 for j >= roundup(i+1,256)
    const bf16_t* Pb = P + (size_t)b * L * ldp + (size_t)m0 * ldp;
    const bf16_t* Vb = VT + (size_t)b * L + (size_t)n0 * ldv;
    ml256x128(Pb, Vb, ldp, ldv, nkt, smem, tid, acc);

    float* Ob = O + (size_t)b * L * Dd;
    const int w = tid >> 6, lane = tid & 63;
    const int wm = w & 3, wn = w >> 2, quad = lane >> 4, l16 = lane & 15;
#pragma unroll
    for (int i = 0; i < 4; ++i) {
        const int row = m0 + wm * 64 + i * 16 + quad * 4;
#pragma unroll
        for (int j = 0; j < 4; ++j) {
            const int col = n0 + wn * 64 + j * 16 + l16;
#pragma unroll
            for (int r = 0; r < 4; ++r)
                Ob[(size_t)(row + r) * Dd + col] = acc[i][j][r];
        }
    }
}

// ---------------------------------------------------------------------------
extern "C" void kernel_launch(void* const* d_in, const int* in_sizes, int n_in,
                              void* d_out, int out_size, void* d_ws, size_t ws_size,
                              hipStream_t stream)
{
    const float* x  = (const float*)d_in[0];
    const float* Wq = (const float*)d_in[1];
    const float* bq = (const float*)d_in[2];
    const float* Wk = (const float*)d_in[3];
    const float* bk = (const float*)d_in[4];
    const float* Wv = (const float*)d_in[5];
    const float* bv = (const float*)d_in[6];
    const int*  len = (const int*)d_in[7];
    float* out = (float*)d_out;

    const int B = 4, L = 2048, D = 1024;
    const int M = B * L;     // 8192
    const int N2 = 2 * D;    // 2048

    // Workspace (~105 MB):
    //  xb [8192][1024] bf16 = 16 MB
    //  WT [3072][1024] bf16 = 6 MB
    //  QK [8192][2048] bf16 = 32 MB  (cols 0:Q 1024:K)
    //  VT [1024][8192] bf16 = 16 MB  (layout [d][b][l])
    //  U  [4][2048][2048] bf16 = 32 MB (blockwise exp -> normalized P in place)
    //  stats [4][2048][32] float2 = 2 MB
    bf16_t* xb = (bf16_t*)d_ws;
    bf16_t* WT = xb + (size_t)M * D;
    bf16_t* QK = WT + (size_t)3 * D * D;
    bf16_t* VT = QK + (size_t)M * N2;
    bf16_t* U  = VT + (size_t)D * M;
    float2* stats = (float2*)(U + (size_t)B * L * L);

    // 1) x -> bf16
    convert_x_kernel<<<(M * D) / 2048, 256, 0, stream>>>(x, xb);

    // 2) all W transposes in one launch
    transpose_w_kernel<<<dim3(32, 32, 3), 256, 0, stream>>>(Wq, Wk, Wv, WT);

    // 3) QK projection (N=2048), 256x256 tiles, 256 blocks
    gemm_qk256<<<dim3(8, 32), 512, 0, stream>>>(xb, WT, bq, bk, QK, N2, D);

    // 4) V^T projection, 256x128 tiles, 256 blocks
    gemm_vt256<<<dim3(64, 4), 512, 0, stream>>>(
        WT + (size_t)2 * D * D, xb, bv, VT, M, D);

    // 5) scores + blockwise softmax -> U (bf16) + stats
    scores256<<<dim3(36, 1, B), 512, 0, stream>>>(
        QK, QK + 1024, N2, len, U, stats, L, D, 0.03125f);

    // 6) finalize stats + normalize U in place -> P
    sm_finalize_norm<<<dim3(L, B), 256, 0, stream>>>(stats, U, L);

    // 7) O = P @ V, causal k-limit, 256 blocks, heavy tiles first
    pv256<<<dim3(8, 8, 4), 512, 0, stream>>>(U, L, VT, M, out, L, D);
}